// Round 1
// baseline (1823.406 us; speedup 1.0000x reference)
//
#include <hip/hip_runtime.h>

#define KDIM 512
#define TDIM 64
#define BDIM 256
#define NWAVE 16
#define BLOCK 1024
#define LOG2E 1.4426950408889634f

__device__ __forceinline__ float wave_reduce_sum(float v) {
    #pragma unroll
    for (int off = 1; off < 64; off <<= 1)
        v += __shfl_xor(v, off, 64);
    return v;
}

// One workgroup per batch element. The entire T-step recurrence runs inside
// the kernel (batches are independent -> no inter-WG communication at all).
__global__ __launch_bounds__(BLOCK) void hmm_forward_kernel(
    const float* __restrict__ x,           // [B, T]
    const float* __restrict__ prior_w,     // [K]
    const float* __restrict__ emission_w,  // [K, 2]
    const float* __restrict__ coeff,       // [K, K]
    const float* __restrict__ bias,        // [K, K]
    float* __restrict__ out)               // [B, K]
{
    __shared__ float post[KDIM];
    __shared__ float em0[KDIM];
    __shared__ float em1[KDIM];
    __shared__ float part[NWAVE][KDIM];   // per-wave pbe partials (32 KB)
    __shared__ float rtmp[NWAVE];

    const int b    = blockIdx.x;
    const int tid  = threadIdx.x;
    const int lane = tid & 63;
    const int wv   = tid >> 6;
    const int k0   = 4 * lane;            // this lane's k-chunk base (and +256)

    // ---- emission softmax over axis=1: em0 = sigmoid(w0 - w1) ----
    if (tid < KDIM) {
        const float w0 = emission_w[2 * tid + 0];
        const float w1 = emission_w[2 * tid + 1];
        const float e0 = 1.0f / (1.0f + exp2f((w1 - w0) * LOG2E));
        em0[tid] = e0;
        em1[tid] = 1.0f - e0;
    }
    __syncthreads();

    // ---- t = 0: post0 = normalize(exp(prior_w) * evidence(x0)) ----
    // (softmax(prior) normalizer cancels in the row-normalize)
    {
        const float x0 = x[b * TDIM + 0];
        float v = 0.0f;
        if (tid < KDIM) {
            const float pr = exp2f(prior_w[tid] * LOG2E);
            const float e  = (1.0f - x0) * em0[tid] + x0 * em1[tid];
            v = pr * e;
        }
        float s = wave_reduce_sum(v);
        if (lane == 0) rtmp[wv] = s;
        __syncthreads();
        if (wv == 0) {
            float t2 = (lane < NWAVE) ? rtmp[lane] : 0.0f;
            #pragma unroll
            for (int off = 1; off < NWAVE; off <<= 1)
                t2 += __shfl_xor(t2, off, 64);
            if (lane == 0) rtmp[0] = t2;
        }
        __syncthreads();
        const float norm = rtmp[0];
        if (tid < KDIM) post[tid] = v / norm;
        __syncthreads();
    }

    // ---- steps t = 1 .. T-1 ----
    for (int t = 1; t < TDIM; ++t) {
        float acc0 = 0.f, acc1 = 0.f, acc2 = 0.f, acc3 = 0.f;
        float acc4 = 0.f, acc5 = 0.f, acc6 = 0.f, acc7 = 0.f;

        // wave wv handles rows j = wv, wv+16, ... (32 rows)
        for (int j = wv; j < KDIM; j += NWAVE) {
            const float p = post[j];            // LDS broadcast, wave-uniform
            if (p != 0.0f) {
                const float4 c0 = *(const float4*)(coeff + j * KDIM + k0);
                const float4 c1 = *(const float4*)(coeff + j * KDIM + 256 + k0);
                const float4 b0 = *(const float4*)(bias  + j * KDIM + k0);
                const float4 b1 = *(const float4*)(bias  + j * KDIM + 256 + k0);

                const float e0 = exp2f((p * c0.x + b0.x) * LOG2E);
                const float e1 = exp2f((p * c0.y + b0.y) * LOG2E);
                const float e2 = exp2f((p * c0.z + b0.z) * LOG2E);
                const float e3 = exp2f((p * c0.w + b0.w) * LOG2E);
                const float e4 = exp2f((p * c1.x + b1.x) * LOG2E);
                const float e5 = exp2f((p * c1.y + b1.y) * LOG2E);
                const float e6 = exp2f((p * c1.z + b1.z) * LOG2E);
                const float e7 = exp2f((p * c1.w + b1.w) * LOG2E);

                // row softmax denominator Z = sum over all 512 k
                float s = ((e0 + e1) + (e2 + e3)) + ((e4 + e5) + (e6 + e7));
                #pragma unroll
                for (int off = 1; off < 64; off <<= 1)
                    s += __shfl_xor(s, off, 64);

                const float scale = p / s;      // post[j] * trans normalizer
                acc0 += scale * e0;  acc1 += scale * e1;
                acc2 += scale * e2;  acc3 += scale * e3;
                acc4 += scale * e4;  acc5 += scale * e5;
                acc6 += scale * e6;  acc7 += scale * e7;
            }
        }

        // combine per-wave partials
        *(float4*)(&part[wv][k0])       = make_float4(acc0, acc1, acc2, acc3);
        *(float4*)(&part[wv][256 + k0]) = make_float4(acc4, acc5, acc6, acc7);
        __syncthreads();

        float v = 0.0f;
        if (tid < KDIM) {
            float pbe = 0.0f;
            #pragma unroll
            for (int w2 = 0; w2 < NWAVE; ++w2) pbe += part[w2][tid];
            const float xt = x[b * TDIM + t];
            const float e  = (1.0f - xt) * em0[tid] + xt * em1[tid];
            v = pbe * e;
        }
        // block reduce for evidence normalizer
        float s = wave_reduce_sum(v);
        if (lane == 0) rtmp[wv] = s;
        __syncthreads();
        if (wv == 0) {
            float t2 = (lane < NWAVE) ? rtmp[lane] : 0.0f;
            #pragma unroll
            for (int off = 1; off < NWAVE; off <<= 1)
                t2 += __shfl_xor(t2, off, 64);
            if (lane == 0) rtmp[0] = t2;
        }
        __syncthreads();
        const float norm = rtmp[0];
        if (tid < KDIM) post[tid] = v / norm;
        __syncthreads();
    }

    if (tid < KDIM) out[b * KDIM + tid] = post[tid];
}

extern "C" void kernel_launch(void* const* d_in, const int* in_sizes, int n_in,
                              void* d_out, int out_size, void* d_ws, size_t ws_size,
                              hipStream_t stream) {
    const float* x          = (const float*)d_in[0];
    const float* prior_w    = (const float*)d_in[1];
    const float* emission_w = (const float*)d_in[2];
    const float* coeff      = (const float*)d_in[3];
    const float* bias       = (const float*)d_in[4];
    float* out              = (float*)d_out;

    hipLaunchKernelGGL(hmm_forward_kernel, dim3(BDIM), dim3(BLOCK), 0, stream,
                       x, prior_w, emission_w, coeff, bias, out);
}